// Round 2
// baseline (11811.618 us; speedup 1.0000x reference)
//
#include <hip/hip_runtime.h>
#include <hip/hip_cooperative_groups.h>

namespace cg = cooperative_groups;

typedef __attribute__((ext_vector_type(8))) short short8;
typedef __attribute__((ext_vector_type(4))) float f32x4;

#define D_DIM 1024
#define H_DIM 1024
#define FH 4096
#define NB 64
#define TT 512
#define MROWS (NB * TT)   // 32768

__device__ __forceinline__ ushort f2bf(float f) {
  union { float f; unsigned u; } v; v.f = f;
  unsigned u = v.u;
  return (ushort)((u + 0x7FFFu + ((u >> 16) & 1u)) >> 16);
}
__device__ __forceinline__ float bf2f(ushort h) {
  union { unsigned u; float f; } v; v.u = ((unsigned)h) << 16;
  return v.f;
}

// ---------------------------------------------------------------------------
// Transpose + fp32->bf16 convert + gate-interleaved column permutation.
// W: [1024][4096] row-major.  WT row r = b*32 + hc_local*4 + gate  maps to
// original column  oc = gate*1024 + b*8 + hc_local.  WT: [4096][1024] bf16.
// grid (64, 16), block 256.
// ---------------------------------------------------------------------------
__global__ void transpose_perm(const float* __restrict__ W, ushort* __restrict__ WT) {
  __shared__ ushort tile[64][65];
  int ocTile = blockIdx.x * 64;
  int kTile  = blockIdx.y * 64;
  int tx = threadIdx.x & 63, ty = threadIdx.x >> 6;
  #pragma unroll
  for (int i = 0; i < 16; ++i) {
    int r = ty + i * 4;  // k offset
    float v = W[(size_t)(kTile + r) * FH + ocTile + tx];
    tile[r][tx] = f2bf(v);
  }
  __syncthreads();
  #pragma unroll
  for (int i = 0; i < 16; ++i) {
    int c = ty + i * 4;              // column offset within tile
    int oc = ocTile + c;
    int gate = oc >> 10, rem = oc & 1023;
    int b = rem >> 3, hcl = rem & 7;
    int r_out = b * 32 + hcl * 4 + gate;
    // WT[oc'][k'] = W[k'][oc']  with oc' = ocTile+c, k' = kTile+tx
    // tile[k_off][oc_off] -> need tile[tx][c]   (BUGFIX: was tile[c][tx])
    WT[(size_t)r_out * D_DIM + kTile + tx] = tile[tx][c];
  }
}

// x fp32 -> bf16, one float4 per thread. grid 32768, block 256.
__global__ void cvt_x(const float* __restrict__ x, ushort* __restrict__ xb) {
  size_t i = (size_t)blockIdx.x * blockDim.x + threadIdx.x;
  const float4* x4 = (const float4*)x;
  float4 v = x4[i];
  ushort4 o; o.x = f2bf(v.x); o.y = f2bf(v.y); o.z = f2bf(v.z); o.w = f2bf(v.w);
  ((ushort4*)xb)[i] = o;
}

// h0 fp32 -> bf16 into h_buf0. grid 256, block 256.
__global__ void cvt_h0(const float* __restrict__ h0, ushort* __restrict__ hb) {
  int i = blockIdx.x * blockDim.x + threadIdx.x;
  hb[i] = f2bf(h0[i]);
}

// ---------------------------------------------------------------------------
// xz GEMM: A = x_bf16 [32768][1024], B = WxT_perm [4096][1024] (both K-contig)
// C written bf16 into xz[t][n][4096] layout (row m = n*512+t scattered).
// 128x128 tile, BK=64, 256 threads (4 waves as 2x2 of 64x64).
// ---------------------------------------------------------------------------
__global__ __launch_bounds__(256) void gemm_xz(const ushort* __restrict__ A,
                                               const ushort* __restrict__ B,
                                               ushort* __restrict__ xz) {
  __shared__ ushort As[128][72];
  __shared__ ushort Bs[128][72];
  int bid = blockIdx.x;
  int nb = bid & 31, mb = bid >> 5;
  int m0 = mb * 128, n0 = nb * 128;
  int tid = threadIdx.x;
  int lane = tid & 63, w = tid >> 6;
  int wm = w >> 1, wn = w & 1;
  int quad = lane >> 4, l15 = lane & 15;

  f32x4 acc[4][4];
  #pragma unroll
  for (int i = 0; i < 4; ++i)
    #pragma unroll
    for (int j = 0; j < 4; ++j) acc[i][j] = (f32x4)0.f;

  for (int k0 = 0; k0 < D_DIM; k0 += 64) {
    #pragma unroll
    for (int q = 0; q < 4; ++q) {
      int seg = q * 256 + tid;          // 0..1023
      int row = seg >> 3, k8 = seg & 7;
      uint4 va = *(const uint4*)(A + (size_t)(m0 + row) * D_DIM + k0 + k8 * 8);
      *(uint4*)(&As[row][k8 * 8]) = va;
      uint4 vb = *(const uint4*)(B + (size_t)(n0 + row) * D_DIM + k0 + k8 * 8);
      *(uint4*)(&Bs[row][k8 * 8]) = vb;
    }
    __syncthreads();
    #pragma unroll
    for (int kc = 0; kc < 2; ++kc) {
      int krow = kc * 32 + quad * 8;
      short8 a[4], b[4];
      #pragma unroll
      for (int mt = 0; mt < 4; ++mt)
        a[mt] = *(const short8*)(&As[wm * 64 + mt * 16 + l15][krow]);
      #pragma unroll
      for (int nt = 0; nt < 4; ++nt)
        b[nt] = *(const short8*)(&Bs[wn * 64 + nt * 16 + l15][krow]);
      #pragma unroll
      for (int mt = 0; mt < 4; ++mt)
        #pragma unroll
        for (int nt = 0; nt < 4; ++nt)
          acc[mt][nt] = __builtin_amdgcn_mfma_f32_16x16x32_bf16(a[mt], b[nt], acc[mt][nt], 0, 0, 0);
    }
    __syncthreads();
  }
  // epilogue: write bf16 into [t][n][4096]
  #pragma unroll
  for (int mt = 0; mt < 4; ++mt)
    #pragma unroll
    for (int nt = 0; nt < 4; ++nt)
      #pragma unroll
      for (int r = 0; r < 4; ++r) {
        int m = m0 + wm * 64 + mt * 16 + quad * 4 + r;
        int n = n0 + wn * 64 + nt * 16 + l15;
        int t = m & 511, nn = m >> 9;
        xz[(size_t)(t * 64 + nn) * FH + n] = f2bf(acc[mt][nt][r]);
      }
}

// ---------------------------------------------------------------------------
// Persistent cooperative LSTM scan.
// 128 blocks x 256 threads. Block owns 32 permuted gate-cols (8 h-cols).
// Wave w holds Wh B-fragments for K-slice [w*256,(w+1)*256) in registers.
// Per step: z_partial = h_prev @ Wh_slice (MFMA, A-frags direct from global),
// K-reduce + gate exchange via LDS, gates in fp32, c in registers,
// h written bf16 (recurrence) + fp32 (output). One grid.sync per step.
// ---------------------------------------------------------------------------
__global__ __launch_bounds__(256, 1) void lstm_scan(
    const ushort* __restrict__ xz,    // [512][64][4096] bf16 (permuted cols)
    const ushort* __restrict__ WhT,   // [4096][1024] bf16 (permuted rows)
    const float*  __restrict__ bias,  // [4096] original order
    ushort* h0buf, ushort* h1buf,     // [64][1024] bf16 ping-pong
    float* __restrict__ out)          // [64][512][1024] fp32
{
  __shared__ float zpart[4 * 64 * 32];
  const int blk = blockIdx.x;     // 0..127
  const int tid = threadIdx.x;
  const int w = tid >> 6;         // wave = K-slice 0..3
  const int lane = tid & 63;
  const int quad = lane >> 4;
  const int l15 = lane & 15;

  // B fragments (Wh slice) -> registers: [nt][kc], K-offset = w*256+kc*32
  short8 bfrag[2][8];
  {
    const ushort* base = WhT + (size_t)(blk * 32) * D_DIM + w * 256;
    #pragma unroll
    for (int nt = 0; nt < 2; ++nt)
      #pragma unroll
      for (int kc = 0; kc < 8; ++kc)
        bfrag[nt][kc] = *(const short8*)(base + (size_t)(nt * 16 + l15) * D_DIM + kc * 32 + quad * 8);
  }

  // gate-phase assignment: thread -> (m = tid>>2, col-quad = tid&3)
  const int gm = tid >> 2;
  const int gq = tid & 3;
  float bb[8];
  #pragma unroll
  for (int j = 0; j < 8; ++j) {
    int c = gq * 8 + j;
    int gate = c & 3, hcl = c >> 2;
    bb[j] = bias[gate * 1024 + blk * 8 + hcl];
  }
  float cst[2] = {0.f, 0.f};

  const ushort* bufs[2] = {h0buf, h1buf};
  cg::grid_group grid = cg::this_grid();

  for (int t = 0; t < TT; ++t) {
    const ushort* rb = bufs[t & 1];
    ushort* wb = (ushort*)bufs[(t + 1) & 1];

    // prefetch xz for this thread's gate-phase cols (hidden under GEMM)
    uint4 xzv = *(const uint4*)(xz + (size_t)(t * 64 + gm) * FH + blk * 32 + gq * 8);

    f32x4 acc[4][2];
    #pragma unroll
    for (int mt = 0; mt < 4; ++mt) { acc[mt][0] = (f32x4)0.f; acc[mt][1] = (f32x4)0.f; }

    #pragma unroll
    for (int kc = 0; kc < 8; ++kc) {
      const ushort* ab = rb + w * 256 + kc * 32 + quad * 8;
      short8 a[4];
      #pragma unroll
      for (int mt = 0; mt < 4; ++mt)
        a[mt] = *(const short8*)(ab + (size_t)(mt * 16 + l15) * H_DIM);
      #pragma unroll
      for (int mt = 0; mt < 4; ++mt) {
        acc[mt][0] = __builtin_amdgcn_mfma_f32_16x16x32_bf16(a[mt], bfrag[0][kc], acc[mt][0], 0, 0, 0);
        acc[mt][1] = __builtin_amdgcn_mfma_f32_16x16x32_bf16(a[mt], bfrag[1][kc], acc[mt][1], 0, 0, 0);
      }
    }

    // write K-partials to LDS: zpart[w][m][col]
    #pragma unroll
    for (int mt = 0; mt < 4; ++mt)
      #pragma unroll
      for (int nt = 0; nt < 2; ++nt)
        #pragma unroll
        for (int r = 0; r < 4; ++r) {
          int m = mt * 16 + quad * 4 + r;
          int col = nt * 16 + l15;
          zpart[(w * 64 + m) * 32 + col] = acc[mt][nt][r];
        }
    __syncthreads();

    // gate phase: 8 cols per thread = 2 h-cols x 4 gates
    float z[8];
    {
      const ushort* xp = (const ushort*)&xzv;
      #pragma unroll
      for (int j = 0; j < 8; ++j) z[j] = bb[j] + bf2f(xp[j]);
      #pragma unroll
      for (int wv = 0; wv < 4; ++wv) {
        const float4* pp = (const float4*)&zpart[(wv * 64 + gm) * 32 + gq * 8];
        float4 p0 = pp[0], p1 = pp[1];
        z[0] += p0.x; z[1] += p0.y; z[2] += p0.z; z[3] += p0.w;
        z[4] += p1.x; z[5] += p1.y; z[6] += p1.z; z[7] += p1.w;
      }
    }
    ushort hpack[2];
    float hout[2];
    #pragma unroll
    for (int p = 0; p < 2; ++p) {
      float ai = z[p * 4 + 0], af = z[p * 4 + 1], ao = z[p * 4 + 2], ag = z[p * 4 + 3];
      float ig = 1.f / (1.f + __expf(-ai));
      float fg = 1.f / (1.f + __expf(-af));
      float og = 1.f / (1.f + __expf(-ao));
      float gg = 2.f / (1.f + __expf(-2.f * ag)) - 1.f;   // tanh
      float c = fg * cst[p] + ig * gg;
      cst[p] = c;
      float th = 2.f / (1.f + __expf(-2.f * c)) - 1.f;    // tanh
      float h = og * th;
      hout[p] = h; hpack[p] = f2bf(h);
    }
    ushort2 hp; hp.x = hpack[0]; hp.y = hpack[1];
    *(ushort2*)(wb + (size_t)gm * H_DIM + blk * 8 + gq * 2) = hp;
    float2 ho; ho.x = hout[0]; ho.y = hout[1];
    *(float2*)(out + ((size_t)gm * TT + t) * H_DIM + blk * 8 + gq * 2) = ho;

    grid.sync();
  }
}

// ---------------------------------------------------------------------------
extern "C" void kernel_launch(void* const* d_in, const int* in_sizes, int n_in,
                              void* d_out, int out_size, void* d_ws, size_t ws_size,
                              hipStream_t stream) {
  const float* x  = (const float*)d_in[0];   // 64*512*1024
  const float* h0 = (const float*)d_in[1];   // 64*1024
  const float* Wx = (const float*)d_in[2];   // 1024*4096
  const float* Wh = (const float*)d_in[3];   // 1024*4096
  const float* b  = (const float*)d_in[4];   // 4096
  float* out = (float*)d_out;

  char* ws = (char*)d_ws;
  ushort* xz    = (ushort*)(ws + 0);                    // 268,435,456 B
  ushort* xb    = (ushort*)(ws + 268435456);            //  67,108,864 B
  ushort* WxT   = (ushort*)(ws + 335544320);            //   8,388,608 B
  ushort* WhT   = (ushort*)(ws + 343932928);            //   8,388,608 B
  ushort* h0buf = (ushort*)(ws + 352321536);            //     131,072 B
  ushort* h1buf = (ushort*)(ws + 352452608);            //     131,072 B

  transpose_perm<<<dim3(64, 16), 256, 0, stream>>>(Wx, WxT);
  transpose_perm<<<dim3(64, 16), 256, 0, stream>>>(Wh, WhT);
  cvt_x<<<32768, 256, 0, stream>>>(x, xb);
  cvt_h0<<<256, 256, 0, stream>>>(h0, h0buf);
  gemm_xz<<<8192, 256, 0, stream>>>(xb, WxT, xz);

  void* args[] = {(void*)&xz, (void*)&WhT, (void*)&b, (void*)&h0buf, (void*)&h1buf, (void*)&out};
  hipLaunchCooperativeKernel((const void*)lstm_scan, dim3(128), dim3(256), args, 0, stream);
}